// Round 1
// baseline (3394.884 us; speedup 1.0000x reference)
//
#include <hip/hip_runtime.h>
#include <hip/hip_bf16.h>
#include <math.h>

// Problem: n=32, c1=c2=512, h=w=64 -> hw=4096. fp32 throughout.
// out = (alpha*softmax_row(att) @ x2 + x1,  beta*softmax_col(att)^T @ x1 + x2)
// att[i][j] = <x1_i, x2_j> / (||x1_i|| * ||x2_j||)   (L2 over spatial dim, eps=1e-12)

#define N_B   32
#define C_    512
#define HW_   4096

// ---------------- row inverse L2 norm: one block per (n,c) row ----------------
__global__ void row_inv_norm(const float* __restrict__ x, float* __restrict__ invn) {
    const size_t row = blockIdx.x;               // 0 .. 32*512-1
    const float* p = x + row * (size_t)HW_;
    const int t = threadIdx.x;                   // 256 threads
    float ss = 0.f;
#pragma unroll
    for (int jj = 0; jj < 4; ++jj) {
        float4 v = *(const float4*)(p + 4 * (t + 256 * jj));
        ss += v.x * v.x + v.y * v.y + v.z * v.z + v.w * v.w;
    }
    __shared__ float red[256];
    red[t] = ss;
    __syncthreads();
    for (int s = 128; s > 0; s >>= 1) {
        if (t < s) red[t] += red[t + s];
        __syncthreads();
    }
    if (t == 0) {
        float nrm = sqrtf(red[0]);
        invn[row] = 1.0f / fmaxf(nrm, 1e-12f);
    }
}

// ---------------- attention GEMM: att = diag(inv1) * (x1 @ x2^T) * diag(inv2) --
// A = x1[n] (512 x 4096), B = x2[n] (512 x 4096), C = att[n] (512 x 512)
// 64x64 block tile, BK=16, 256 threads (16x16), 4x4 micro-tile.
__global__ void attn_gemm(const float* __restrict__ x1, const float* __restrict__ x2,
                          const float* __restrict__ inv1, const float* __restrict__ inv2,
                          float* __restrict__ att) {
    const int n  = blockIdx.z;
    const int j0 = blockIdx.x * 64;
    const int m0 = blockIdx.y * 64;
    const float* A = x1 + (size_t)n * C_ * HW_;
    const float* B = x2 + (size_t)n * C_ * HW_;

    __shared__ float As[16][68];   // [k][m], stride 68 keeps float4 reads aligned
    __shared__ float Bs[16][68];   // [k][j]

    const int t   = threadIdx.x;
    const int tx  = t & 15, ty = t >> 4;
    const int lr  = t >> 2;          // 0..63 tile row
    const int lc4 = (t & 3) * 4;     // k offset 0,4,8,12

    float acc[4][4] = {};

    for (int k0 = 0; k0 < HW_; k0 += 16) {
        float4 av = *(const float4*)(A + (size_t)(m0 + lr) * HW_ + k0 + lc4);
        float4 bv = *(const float4*)(B + (size_t)(j0 + lr) * HW_ + k0 + lc4);
        __syncthreads();
        As[lc4 + 0][lr] = av.x; As[lc4 + 1][lr] = av.y;
        As[lc4 + 2][lr] = av.z; As[lc4 + 3][lr] = av.w;
        Bs[lc4 + 0][lr] = bv.x; Bs[lc4 + 1][lr] = bv.y;
        Bs[lc4 + 2][lr] = bv.z; Bs[lc4 + 3][lr] = bv.w;
        __syncthreads();
#pragma unroll
        for (int k = 0; k < 16; ++k) {
            float4 a4 = *(const float4*)&As[k][ty * 4];
            float4 b4 = *(const float4*)&Bs[k][tx * 4];
            float ar[4] = {a4.x, a4.y, a4.z, a4.w};
            float br[4] = {b4.x, b4.y, b4.z, b4.w};
#pragma unroll
            for (int i = 0; i < 4; ++i)
#pragma unroll
                for (int j = 0; j < 4; ++j)
                    acc[i][j] += ar[i] * br[j];
        }
    }

    float s1[4], s2[4];
#pragma unroll
    for (int i = 0; i < 4; ++i) {
        s1[i] = inv1[n * C_ + m0 + ty * 4 + i];
        s2[i] = inv2[n * C_ + j0 + tx * 4 + i];
    }
#pragma unroll
    for (int i = 0; i < 4; ++i) {
        float4 o;
        o.x = acc[i][0] * s1[i] * s2[0];
        o.y = acc[i][1] * s1[i] * s2[1];
        o.z = acc[i][2] * s1[i] * s2[2];
        o.w = acc[i][3] * s1[i] * s2[3];
        *(float4*)&att[((size_t)n * C_ + m0 + ty * 4 + i) * C_ + j0 + tx * 4] = o;
    }
}

// ---------------- row softmax (over j / c2), in place on att ----------------
__global__ void row_softmax(float* __restrict__ att) {
    const size_t row = blockIdx.x;               // n*512 + i
    float* p = att + row * (size_t)C_;
    const int t = threadIdx.x;                   // 256
    float v0 = p[t], v1 = p[t + 256];
    __shared__ float red[256];
    red[t] = fmaxf(v0, v1);
    __syncthreads();
    for (int s = 128; s > 0; s >>= 1) {
        if (t < s) red[t] = fmaxf(red[t], red[t + s]);
        __syncthreads();
    }
    const float M = red[0];
    __syncthreads();
    float e0 = expf(v0 - M), e1 = expf(v1 - M);
    red[t] = e0 + e1;
    __syncthreads();
    for (int s = 128; s > 0; s >>= 1) {
        if (t < s) red[t] += red[t + s];
        __syncthreads();
    }
    const float inv = 1.0f / red[0];
    p[t] = e0 * inv;
    p[t + 256] = e1 * inv;
}

// ---------------- column softmax (over i / c1), writes attn2[n][j][i] ----------
// Block: (jgroup of 64, n). 256 threads: 4 slices of 128 rows x 64 columns.
__global__ void col_softmax(const float* __restrict__ att, float* __restrict__ attn2) {
    const int n  = blockIdx.y;
    const int j0 = blockIdx.x * 64;
    const int t  = threadIdx.x;
    const int col = j0 + (t & 63);
    const int sl  = t >> 6;                      // 0..3
    const float* base = att + (size_t)n * C_ * C_;

    float m = -INFINITY, l = 0.f;
    for (int i = sl * 128; i < sl * 128 + 128; ++i) {
        float v = base[(size_t)i * C_ + col];
        float mn = fmaxf(m, v);
        l = l * expf(m - mn) + expf(v - mn);
        m = mn;
    }
    __shared__ float ms[4][64], ls[4][64];
    ms[sl][t & 63] = m;
    ls[sl][t & 63] = l;
    __syncthreads();
    float M = fmaxf(fmaxf(ms[0][t & 63], ms[1][t & 63]),
                    fmaxf(ms[2][t & 63], ms[3][t & 63]));
    float L = 0.f;
#pragma unroll
    for (int s = 0; s < 4; ++s) L += ls[s][t & 63] * expf(ms[s][t & 63] - M);
    const float inv = 1.0f / L;
    float* outp = attn2 + ((size_t)n * C_ + col) * C_;
    for (int i = sl * 128; i < sl * 128 + 128; ++i) {
        outp[i] = expf(base[(size_t)i * C_ + col] - M) * inv;
    }
}

// ---------------- second-stage GEMM + epilogue out = scal*(A@B) + X -----------
// ATRANS=true : A is [M x K] row-major (attn1)            -> transposed LDS store
// ATRANS=false: A is [K x M] row-major (attn2 as [j][i], used as A^T) -> natural
// B is [K x N] row-major (x2 or x1). M=512, N=4096, K=512.
template <bool ATRANS>
__global__ void gemm_epi(const float* __restrict__ Aall, const float* __restrict__ Ball,
                         const float* __restrict__ Xall, const float* __restrict__ scal,
                         float* __restrict__ outAll) {
    constexpr int M = 512, N = 4096, K = 512;
    const int n  = blockIdx.z;
    const int j0 = blockIdx.x * 64;
    const int m0 = blockIdx.y * 64;
    const float* A = Aall + (size_t)n * M * K;
    const float* B = Ball + (size_t)n * K * N;
    const float* X = Xall + (size_t)n * M * N;
    float* out = outAll + (size_t)n * M * N;

    __shared__ float As[16][68];   // [k][m]
    __shared__ float Bs[16][68];   // [k][j]

    const int t   = threadIdx.x;
    const int tx  = t & 15, ty = t >> 4;
    const int lr  = t >> 2;          // A rows (ATRANS)
    const int lc4 = (t & 3) * 4;     // A k-cols (ATRANS)
    const int rB  = t >> 4;          // k row (B tile and !ATRANS A tile)
    const int cB  = (t & 15) * 4;    // col

    const float sc = scal[0];
    float acc[4][4] = {};

    for (int k0 = 0; k0 < K; k0 += 16) {
        float4 av, bv;
        if (ATRANS)
            av = *(const float4*)(A + (size_t)(m0 + lr) * K + k0 + lc4);
        else
            av = *(const float4*)(A + (size_t)(k0 + rB) * M + m0 + cB);
        bv = *(const float4*)(B + (size_t)(k0 + rB) * N + j0 + cB);
        __syncthreads();
        if (ATRANS) {
            As[lc4 + 0][lr] = av.x; As[lc4 + 1][lr] = av.y;
            As[lc4 + 2][lr] = av.z; As[lc4 + 3][lr] = av.w;
        } else {
            *(float4*)&As[rB][cB] = av;
        }
        *(float4*)&Bs[rB][cB] = bv;
        __syncthreads();
#pragma unroll
        for (int k = 0; k < 16; ++k) {
            float4 a4 = *(const float4*)&As[k][ty * 4];
            float4 b4 = *(const float4*)&Bs[k][tx * 4];
            float ar[4] = {a4.x, a4.y, a4.z, a4.w};
            float br[4] = {b4.x, b4.y, b4.z, b4.w};
#pragma unroll
            for (int i = 0; i < 4; ++i)
#pragma unroll
                for (int j = 0; j < 4; ++j)
                    acc[i][j] += ar[i] * br[j];
        }
    }

#pragma unroll
    for (int i = 0; i < 4; ++i) {
        const int m = m0 + ty * 4 + i;
        const size_t idx = (size_t)m * N + j0 + tx * 4;
        float4 xv = *(const float4*)&X[idx];
        float4 o;
        o.x = sc * acc[i][0] + xv.x;
        o.y = sc * acc[i][1] + xv.y;
        o.z = sc * acc[i][2] + xv.z;
        o.w = sc * acc[i][3] + xv.w;
        *(float4*)&out[idx] = o;
    }
}

extern "C" void kernel_launch(void* const* d_in, const int* in_sizes, int n_in,
                              void* d_out, int out_size, void* d_ws, size_t ws_size,
                              hipStream_t stream) {
    const float* x1    = (const float*)d_in[0];
    const float* x2    = (const float*)d_in[1];
    const float* alpha = (const float*)d_in[2];
    const float* beta  = (const float*)d_in[3];
    float* out = (float*)d_out;

    // Workspace plan (needs ~33.7 MB):
    //   inv1: 16384 f32 | inv2: 16384 f32 | att: 32*512*512 f32 (32 MB)
    // attn2 (col-softmaxed, [n][j][i]) is staged in the out1 region of d_out
    // (32 MB of 256 MB) and fully consumed by gemm3 BEFORE gemm2 overwrites
    // out1 — stream ordering guarantees this.
    float* inv1  = (float*)d_ws;
    float* inv2  = inv1 + (size_t)N_B * C_;
    float* att   = inv2 + (size_t)N_B * C_;
    float* attn2 = out;                                   // staged in out1 region
    float* out1  = out;
    float* out2  = out + (size_t)N_B * C_ * HW_;

    row_inv_norm<<<N_B * C_, 256, 0, stream>>>(x1, inv1);
    row_inv_norm<<<N_B * C_, 256, 0, stream>>>(x2, inv2);

    attn_gemm<<<dim3(8, 8, N_B), 256, 0, stream>>>(x1, x2, inv1, inv2, att);

    col_softmax<<<dim3(8, N_B), 256, 0, stream>>>(att, attn2);

    // gemm3 first: consumes attn2 (living in out1 region), writes out2.
    gemm_epi<false><<<dim3(64, 8, N_B), 256, 0, stream>>>(attn2, x1, x2, beta, out2);

    // row softmax in place on att (att no longer needed raw), then gemm2 -> out1.
    row_softmax<<<N_B * C_, 256, 0, stream>>>(att);
    gemm_epi<true><<<dim3(64, 8, N_B), 256, 0, stream>>>(att, x2, x1, alpha, out1);
}